// Round 4
// baseline (762.738 us; speedup 1.0000x reference)
//
#include <hip/hip_runtime.h>
#include <math.h>

// Problem constants (fixed by reference setup_inputs)
#define E_ 4
#define L_ 10
#define S_ 1024
#define F_ 256
#define T_ 1024
#define NROW (E_*L_*S_)          // 40960 rows of the GEMM
#define KPAD 512                 // max conv half-support (padding)
#define NPAD (KPAD + T_ + KPAD + 8)   // 2056 floats per padded w-plane
#define GS_HALF 512
#define GS_LEN 1040              // symmetric tap table, zero-padded

// workspace layout (float indices)
#define OFF_GS   32
#define OFF_ET   2048
#define OFF_M    4096
#define OFF_W    (4096 + (size_t)NROW * F_)

__device__ __forceinline__ unsigned int encf(float x) {
  unsigned int b = __float_as_uint(x);
  return (b & 0x80000000u) ? ~b : (b | 0x80000000u);
}
__device__ __forceinline__ float decf(unsigned int u) {
  unsigned int b = (u & 0x80000000u) ? (u ^ 0x80000000u) : ~u;
  return __uint_as_float(b);
}
__device__ __forceinline__ void fma4(float4& c, float s, const float4& p) {
  c.x = fmaf(s, p.x, c.x); c.y = fmaf(s, p.y, c.y);
  c.z = fmaf(s, p.z, c.z); c.w = fmaf(s, p.w, c.w);
}

// K0: m = matrix @ params (fp32), layout unchanged (e,l,s,f); fused global min/max.
// P staged in LDS in 64-row chunks (64 KB). Wave handles 16 rows; A loads are
// wave-uniform -> scalar loads. Thread: 16 rows x 4 g (float4 acc), acc lives
// across the 4 P-chunks.
__global__ __launch_bounds__(256) void k0_gemm(const float* __restrict__ A,
                                               const float* __restrict__ P,
                                               float* __restrict__ M,
                                               unsigned int* __restrict__ slots) {
  __shared__ __align__(16) float Pl[64 * F_];   // 64 KB
  const int tid = threadIdx.x;
  const int lane = tid & 63;
  const int wv = __builtin_amdgcn_readfirstlane(tid >> 6);
  const int row0 = blockIdx.x * 64 + wv * 16;
  const int g4 = lane * 4;
  float4 acc[16];
#pragma unroll
  for (int r = 0; r < 16; ++r) acc[r] = make_float4(0.f, 0.f, 0.f, 0.f);
  for (int fc = 0; fc < F_; fc += 64) {
    __syncthreads();
    {
      const float4* Ps = (const float4*)(P + (size_t)fc * F_);
      float4* Pd = (float4*)Pl;
      for (int i = tid; i < 64 * F_ / 4; i += 256) Pd[i] = Ps[i];
    }
    __syncthreads();
    for (int f0 = 0; f0 < 64; f0 += 4) {
      float4 p0 = *(const float4*)&Pl[(f0 + 0) * F_ + g4];
      float4 p1 = *(const float4*)&Pl[(f0 + 1) * F_ + g4];
      float4 p2 = *(const float4*)&Pl[(f0 + 2) * F_ + g4];
      float4 p3 = *(const float4*)&Pl[(f0 + 3) * F_ + g4];
#pragma unroll
      for (int r = 0; r < 16; ++r) {
        float4 a = *(const float4*)&A[(size_t)(row0 + r) * F_ + fc + f0]; // uniform
        fma4(acc[r], a.x, p0); fma4(acc[r], a.y, p1);
        fma4(acc[r], a.z, p2); fma4(acc[r], a.w, p3);
      }
    }
  }
  float vmin = 3.4e38f, vmax = -3.4e38f;
#pragma unroll
  for (int r = 0; r < 16; ++r) {
    *(float4*)&M[(size_t)(row0 + r) * F_ + g4] = acc[r];
    vmin = fminf(vmin, fminf(fminf(acc[r].x, acc[r].y), fminf(acc[r].z, acc[r].w)));
    vmax = fmaxf(vmax, fmaxf(fmaxf(acc[r].x, acc[r].y), fmaxf(acc[r].z, acc[r].w)));
  }
#pragma unroll
  for (int off = 32; off; off >>= 1) {
    vmin = fminf(vmin, __shfl_down(vmin, off));
    vmax = fmaxf(vmax, __shfl_down(vmax, off));
  }
  if (lane == 0) {
    atomicMin(&slots[0], encf(vmin));
    atomicMax(&slots[1], encf(vmax));
  }
}

// K1: grid constants + symmetric zero-padded Gaussian tap table + exp(c*x_t^2) table.
__global__ __launch_bounds__(256) void k1_setup(const unsigned int* __restrict__ slots,
                                                float* __restrict__ hdr,
                                                int* __restrict__ hdri,
                                                float* __restrict__ Gs,
                                                float* __restrict__ et) {
  const float left = decf(slots[0]);
  const float right = decf(slots[1]);
  const float dg = (right - left) / 1023.0f;    // linspace step (1024 pts)
  const float inv_dg = 1.0f / dg;
  const float delta = (right - left) / 1024.0f; // reference's delta
  const float divisor = 0.62665706865775006f;   // sqrt(2*pi)*0.25
  const float scale = delta * 0.5f / divisor;
  int kmax = (int)(2.39792f * inv_dg) + 1;      // exp(-8u^2)<1e-20 beyond
  if (kmax > KPAD - 8) kmax = KPAD - 8;
  const int K4 = (kmax + 4) & ~3;
  const int tid = threadIdx.x;
  if (tid == 0) {
    hdr[0] = left; hdr[1] = dg; hdr[2] = inv_dg; hdr[3] = scale;
    hdri[4] = K4;
  }
  const float c = -8.0f;
  for (int j = tid; j < GS_LEN; j += 256) {
    int k = j - GS_HALF;
    int ak = k < 0 ? -k : k;
    float u = (float)k * dg;
    Gs[j] = (ak <= kmax) ? expf(c * u * u) : 0.0f;
  }
  for (int t = tid; t < T_; t += 256) {
    float x = left + (float)t * dg;
    et[t] = expf(c * x * x);
  }
}

// K2: linear binning. Block = (e,l) x 16-column group; 16x1024 fp32 bins in LDS.
__global__ __launch_bounds__(256) void k2_bin(const float* __restrict__ M,
                                              const float* __restrict__ hdr,
                                              float* __restrict__ wbuf) {
  __shared__ float wl[16][T_];   // 64 KB
  const int tid = threadIdx.x;
  const int el = blockIdx.x >> 4;
  const int fg = blockIdx.x & 15;
  {
    float4* z = (float4*)&wl[0][0];
    for (int i = tid; i < 16 * T_ / 4; i += 256) z[i] = make_float4(0.f, 0.f, 0.f, 0.f);
  }
  __syncthreads();
  const float left = hdr[0];
  const float inv_dg = hdr[2];
  const int fs = tid & 15;
  const int ss = tid >> 4;
  const float* base = M + (size_t)el * S_ * F_ + fg * 16 + fs;
  for (int s = ss; s < S_; s += 16) {
    float v = base[(size_t)s * F_];
    float p = (v - left) * inv_dg;
    int j = (int)p;
    if (j > 1022) j = 1022;
    float a = p - (float)j;
    atomicAdd(&wl[fs][j], 1.0f - a);
    atomicAdd(&wl[fs][j + 1], a);
  }
  __syncthreads();
  float* out = wbuf + ((size_t)el * F_ + fg * 16) * T_;
  const float* src = (const float*)wl;
  for (int i = tid; i < 16 * T_; i += 256) out[i] = src[i];
}

// K3: per-(l,f) block, 256 threads, 4 grid points per thread (t = 4*tid).
// All LDS reads are the canonical contiguous pattern (lane i -> 16*i bytes):
// conflict-free by construction. Sliding 8-float window, 1 new ds_read_b128
// per 4 taps per plane, 16 FMA per read.
__global__ __launch_bounds__(256) void k3_conv(const float* __restrict__ wbuf,
                                               const float* __restrict__ Gs,
                                               const float* __restrict__ et,
                                               const float* __restrict__ hdr,
                                               const int* __restrict__ hdri,
                                               const float* __restrict__ dl,
                                               float* __restrict__ out) {
  __shared__ __align__(16) float wpad[E_][NPAD];  // ~32.9 KB
  __shared__ float rs[4][6];
  const int tid = threadIdx.x;
  const int l = blockIdx.x >> 8;
  const int f = blockIdx.x & 255;
  {
    float4* z = (float4*)&wpad[0][0];
    const int n4 = E_ * NPAD / 4;
    for (int i = tid; i < n4; i += 256) z[i] = make_float4(0.f, 0.f, 0.f, 0.f);
  }
  __syncthreads();
#pragma unroll
  for (int e = 0; e < E_; ++e) {
    const float4* src = (const float4*)(wbuf + ((size_t)(e * L_ + l) * F_ + f) * T_);
    float4 v0 = src[tid];
    *(float4*)&wpad[e][KPAD + 4 * tid] = v0;   // stride 16 B: canonical
  }
  __syncthreads();
  const int K4 = hdri[4];
  const float scale = hdr[3];
  const int base = KPAD + 4 * tid;
  float acc[E_][4];
#pragma unroll
  for (int e = 0; e < E_; ++e)
#pragma unroll
    for (int d = 0; d < 4; ++d) acc[e][d] = 0.f;
  float4 A0[E_];
#pragma unroll
  for (int e = 0; e < E_; ++e)
    A0[e] = *(const float4*)&wpad[e][base - K4];
  for (int k0 = -K4; k0 < K4; k0 += 4) {
    const float4 g4 = *(const float4*)(Gs + GS_HALF + k0);  // uniform -> s_load
#pragma unroll
    for (int e = 0; e < E_; ++e) {
      float4 A1 = *(const float4*)&wpad[e][base + k0 + 4];  // stride 16 B: canonical
      float W[8] = {A0[e].x, A0[e].y, A0[e].z, A0[e].w,
                    A1.x,    A1.y,    A1.z,    A1.w};
#pragma unroll
      for (int kk = 0; kk < 4; ++kk) {
        const float g = (kk == 0) ? g4.x : (kk == 1) ? g4.y : (kk == 2) ? g4.z : g4.w;
#pragma unroll
        for (int d = 0; d < 4; ++d)
          acc[e][d] = fmaf(W[d + kk], g, acc[e][d]);
      }
      A0[e] = A1;
    }
  }
  // epilogue: red = (ksum - (S-dl)*et)/dl, pairwise |diff| sums
  float etv[4];
  {
    float4 e0 = *(const float4*)(et + 4 * tid);
    etv[0] = e0.x; etv[1] = e0.y; etv[2] = e0.z; etv[3] = e0.w;
  }
  float red[E_][4];
#pragma unroll
  for (int e = 0; e < E_; ++e) {
    const float dlv = dl[e * L_ + l];
    const float zc = (float)S_ - dlv;
    const float idl = 1.0f / dlv;
#pragma unroll
    for (int d = 0; d < 4; ++d)
      red[e][d] = (acc[e][d] - zc * etv[d]) * idl;
  }
  float D[6];
  const int pa[6] = {0, 0, 0, 1, 1, 2};
  const int pb[6] = {1, 2, 3, 2, 3, 3};
#pragma unroll
  for (int p = 0; p < 6; ++p) {
    float s = 0.f;
#pragma unroll
    for (int d = 0; d < 4; ++d) s += fabsf(red[pa[p]][d] - red[pb[p]][d]);
    D[p] = s;
  }
#pragma unroll
  for (int off = 32; off; off >>= 1)
#pragma unroll
    for (int p = 0; p < 6; ++p) D[p] += __shfl_down(D[p], off);
  if ((tid & 63) == 0) {
#pragma unroll
    for (int p = 0; p < 6; ++p) rs[tid >> 6][p] = D[p];
  }
  __syncthreads();
  if (tid == 0) {
    float Tp[6];
#pragma unroll
    for (int p = 0; p < 6; ++p)
      Tp[p] = (rs[0][p] + rs[1][p] + rs[2][p] + rs[3][p]) * scale;
    float test = Tp[0];
#pragma unroll
    for (int p = 1; p < 6; ++p) test = fmaxf(test, Tp[p]);
    float train = fmaxf(fmaxf(Tp[1], Tp[2]), Tp[5]);
    out[l * F_ + f] = train;                 // train_results
    out[L_ * F_ + l * F_ + f] = test;        // test_results
  }
}

extern "C" void kernel_launch(void* const* d_in, const int* in_sizes, int n_in,
                              void* d_out, int out_size, void* d_ws, size_t ws_size,
                              hipStream_t stream) {
  const float* A  = (const float*)d_in[0];   // matrix (4,10,1024,256)
  const float* dl = (const float*)d_in[1];   // data_len (4,10)
  const float* P  = (const float*)d_in[2];   // params (256,256)
  float* out = (float*)d_out;
  float* ws = (float*)d_ws;
  float* hdr = ws;
  int* hdri = (int*)d_ws;
  unsigned int* slots = (unsigned int*)(ws + 16);
  float* Gs = ws + OFF_GS;
  float* et = ws + OFF_ET;
  float* M  = ws + OFF_M;
  float* wb = ws + OFF_W;

  (void)hipMemsetAsync(slots, 0xFF, 4, stream);      // min slot neutral
  (void)hipMemsetAsync(slots + 1, 0x00, 4, stream);  // max slot neutral

  k0_gemm<<<NROW / 64, 256, 0, stream>>>(A, P, M, slots);
  k1_setup<<<1, 256, 0, stream>>>(slots, hdr, hdri, Gs, et);
  k2_bin<<<(E_ * L_) * (F_ / 16), 256, 0, stream>>>(M, hdr, wb);
  k3_conv<<<L_ * F_, 256, 0, stream>>>(wb, Gs, et, hdr, hdri, dl, out);
}

// Round 5
// 450.314 us; speedup vs baseline: 1.6938x; 1.6938x over previous
//
#include <hip/hip_runtime.h>
#include <hip/hip_fp16.h>
#include <math.h>

// Problem constants (fixed by reference setup_inputs)
#define E_ 4
#define L_ 10
#define S_ 1024
#define F_ 256
#define T_ 1024
#define NROW (E_*L_*S_)     // 40960 rows of the input GEMM
#define KPAD2 384           // left pad of each padded W row (halfs), mult of 8
#define WROW 1920           // padded W row stride in halfs (384+1024+512)
#define TTW  864            // Toeplitz block width (a-dim), covers 2*K4max+96

// workspace layout (float indices). OUT aliases M (M dead after k2).
#define OFF_TT  64                       // f16 TT[64][864] = 55296 halfs = 27648 floats
#define OFF_M   32768                    // fp32 M, 40960*256 floats (= OUT alias)
#define OFF_WH  (32768 + (size_t)NROW * F_)  // f16 padded W planes, 40*256*1920 halfs

typedef _Float16 half8 __attribute__((ext_vector_type(8)));
typedef float f32x4v __attribute__((ext_vector_type(4)));

__device__ __forceinline__ unsigned int encf(float x) {
  unsigned int b = __float_as_uint(x);
  return (b & 0x80000000u) ? ~b : (b | 0x80000000u);
}
__device__ __forceinline__ float decf(unsigned int u) {
  unsigned int b = (u & 0x80000000u) ? (u ^ 0x80000000u) : ~u;
  return __uint_as_float(b);
}
__device__ __forceinline__ void fma4(float4& c, float s, const float4& p) {
  c.x = fmaf(s, p.x, c.x); c.y = fmaf(s, p.y, c.y);
  c.z = fmaf(s, p.z, c.z); c.w = fmaf(s, p.w, c.w);
}

// K0: m = matrix @ params (fp32), fused global min/max (unchanged, validated).
__global__ __launch_bounds__(256) void k0_gemm(const float* __restrict__ A,
                                               const float* __restrict__ P,
                                               float* __restrict__ M,
                                               unsigned int* __restrict__ slots) {
  __shared__ __align__(16) float Pl[64 * F_];   // 64 KB
  const int tid = threadIdx.x;
  const int lane = tid & 63;
  const int wv = __builtin_amdgcn_readfirstlane(tid >> 6);
  const int row0 = blockIdx.x * 64 + wv * 16;
  const int g4 = lane * 4;
  float4 acc[16];
#pragma unroll
  for (int r = 0; r < 16; ++r) acc[r] = make_float4(0.f, 0.f, 0.f, 0.f);
  for (int fc = 0; fc < F_; fc += 64) {
    __syncthreads();
    {
      const float4* Ps = (const float4*)(P + (size_t)fc * F_);
      float4* Pd = (float4*)Pl;
      for (int i = tid; i < 64 * F_ / 4; i += 256) Pd[i] = Ps[i];
    }
    __syncthreads();
    for (int f0 = 0; f0 < 64; f0 += 4) {
      float4 p0 = *(const float4*)&Pl[(f0 + 0) * F_ + g4];
      float4 p1 = *(const float4*)&Pl[(f0 + 1) * F_ + g4];
      float4 p2 = *(const float4*)&Pl[(f0 + 2) * F_ + g4];
      float4 p3 = *(const float4*)&Pl[(f0 + 3) * F_ + g4];
#pragma unroll
      for (int r = 0; r < 16; ++r) {
        float4 a = *(const float4*)&A[(size_t)(row0 + r) * F_ + fc + f0]; // uniform
        fma4(acc[r], a.x, p0); fma4(acc[r], a.y, p1);
        fma4(acc[r], a.z, p2); fma4(acc[r], a.w, p3);
      }
    }
  }
  float vmin = 3.4e38f, vmax = -3.4e38f;
#pragma unroll
  for (int r = 0; r < 16; ++r) {
    *(float4*)&M[(size_t)(row0 + r) * F_ + g4] = acc[r];
    vmin = fminf(vmin, fminf(fminf(acc[r].x, acc[r].y), fminf(acc[r].z, acc[r].w)));
    vmax = fmaxf(vmax, fmaxf(fmaxf(acc[r].x, acc[r].y), fmaxf(acc[r].z, acc[r].w)));
  }
#pragma unroll
  for (int off = 32; off; off >>= 1) {
    vmin = fminf(vmin, __shfl_down(vmin, off));
    vmax = fmaxf(vmax, __shfl_down(vmax, off));
  }
  if (lane == 0) {
    atomicMin(&slots[0], encf(vmin));
    atomicMax(&slots[1], encf(vmax));
  }
}

// K1: grid constants only (1 block).
__global__ __launch_bounds__(64) void k1_setup(const unsigned int* __restrict__ slots,
                                               float* __restrict__ hdr,
                                               int* __restrict__ hdri) {
  if (threadIdx.x == 0) {
    const float left = decf(slots[0]);
    const float right = decf(slots[1]);
    const float dg = (right - left) / 1023.0f;    // linspace step (1024 pts)
    const float inv_dg = 1.0f / dg;
    const float delta = (right - left) / 1024.0f; // reference's delta
    const float divisor = 0.62665706865775006f;   // sqrt(2*pi)*0.25
    const float scale = delta * 0.5f / divisor;
    int kmax = (int)(2.39792f * inv_dg) + 1;      // exp(-8u^2)<1e-20 beyond
    if (kmax > 368) kmax = 368;
    const int K4 = (kmax + 8) & ~7;               // mult of 8, > kmax, <= 376
    hdr[0] = left; hdr[1] = dg; hdr[2] = inv_dg; hdr[3] = scale;
    hdri[4] = K4; hdri[5] = kmax;
  }
}

// K1b: Toeplitz block TT[b][ak] = G(b + K4 - ak), f16. One block per b row.
__global__ __launch_bounds__(256) void k1b_tt(const float* __restrict__ hdr,
                                              const int* __restrict__ hdri,
                                              __half* __restrict__ TT) {
  const int b = blockIdx.x;
  const float dg = hdr[1];
  const int K4 = hdri[4], kmax = hdri[5];
  for (int ak = threadIdx.x; ak < TTW; ak += 256) {
    int d = b + K4 - ak;
    int ad = d < 0 ? -d : d;
    float u = (float)d * dg;
    float v = (ad <= kmax) ? expf(-8.0f * u * u) : 0.0f;
    TT[(size_t)b * TTW + ak] = __float2half(v);
  }
}

// K2: linear binning into fp32 LDS bins, then write padded f16 W rows.
__global__ __launch_bounds__(256) void k2_bin(const float* __restrict__ M,
                                              const float* __restrict__ hdr,
                                              __half* __restrict__ Wh) {
  __shared__ float wl[16][T_];   // 64 KB
  const int tid = threadIdx.x;
  const int el = blockIdx.x >> 4;
  const int fg = blockIdx.x & 15;
  {
    float4* z = (float4*)&wl[0][0];
    for (int i = tid; i < 16 * T_ / 4; i += 256) z[i] = make_float4(0.f, 0.f, 0.f, 0.f);
  }
  __syncthreads();
  const float left = hdr[0];
  const float inv_dg = hdr[2];
  const int fs = tid & 15;
  const int ss = tid >> 4;
  const float* base = M + (size_t)el * S_ * F_ + fg * 16 + fs;
  for (int s = ss; s < S_; s += 16) {
    float v = base[(size_t)s * F_];
    float p = (v - left) * inv_dg;
    int j = (int)p;
    if (j > 1022) j = 1022;
    float a = p - (float)j;
    atomicAdd(&wl[fs][j], 1.0f - a);
    atomicAdd(&wl[fs][j + 1], a);
  }
  __syncthreads();
  __half* wrow = Wh + ((size_t)el * F_ + fg * 16) * WROW;
  // main region: 16 rows x 1024 halfs
  for (int i = tid; i < 16 * 512; i += 256) {
    int r = i >> 9, c2 = i & 511;
    *(__half2*)(wrow + (size_t)r * WROW + KPAD2 + 2 * c2) =
        __floats2half2_rn(wl[r][2 * c2], wl[r][2 * c2 + 1]);
  }
  // pads: left [0,384) = 192 half2, right [1408,1920) = 256 half2 -> 448/row
  for (int i = tid; i < 16 * 448; i += 256) {
    int r = i / 448, p = i % 448;
    int col = (p < 192) ? 2 * p : (1408 + 2 * (p - 192));
    *(__half2*)(wrow + (size_t)r * WROW + col) = __floats2half2_rn(0.f, 0.f);
  }
}

// K3: banded-Toeplitz GEMM via MFMA f32_16x16x32_f16.
// Block = (el, t-tile of 64): OUT[el][f=0..255][t0..t0+63] = W x TT.
// 4 waves; wave w owns f in [64w, 64w+64): 4x4 grid of 16x16 MFMA tiles.
__global__ __launch_bounds__(256) void k3_mfma(const _Float16* __restrict__ Wh,
                                               const _Float16* __restrict__ TT,
                                               const int* __restrict__ hdri,
                                               float* __restrict__ OUT) {
  __shared__ __align__(16) _Float16 Wl[256][40];  // 20 KB, row 80 B
  const int tid = threadIdx.x;
  const int wave = tid >> 6, lane = tid & 63;
  const int nn = lane & 15, quad = lane >> 4;
  const int el = blockIdx.x >> 4;
  const int t0 = (blockIdx.x & 15) << 6;
  const int K4 = hdri[4];
  const int nkc = (2 * K4 + 64 + 31) >> 5;
  const _Float16* Wp = Wh + (size_t)el * F_ * WROW + (KPAD2 - K4 + t0);
  f32x4v acc[4][4];
#pragma unroll
  for (int ft = 0; ft < 4; ++ft)
#pragma unroll
    for (int tn = 0; tn < 4; ++tn) acc[ft][tn] = (f32x4v){0.f, 0.f, 0.f, 0.f};
  for (int kc = 0; kc < nkc; ++kc) {
    __syncthreads();
    {
      const int4* s = (const int4*)(Wp + (size_t)tid * WROW + kc * 32);
      int4 v0 = s[0], v1 = s[1], v2 = s[2], v3 = s[3];
      int4* d = (int4*)&Wl[tid][0];
      d[0] = v0; d[1] = v1; d[2] = v2; d[3] = v3;
    }
    __syncthreads();
    half8 bf[4];
#pragma unroll
    for (int tn = 0; tn < 4; ++tn)
      bf[tn] = *(const half8*)(TT + (size_t)(tn * 16 + nn) * TTW + kc * 32 + quad * 8);
#pragma unroll
    for (int ft = 0; ft < 4; ++ft) {
      half8 af = *(const half8*)&Wl[wave * 64 + ft * 16 + nn][quad * 8];
#pragma unroll
      for (int tn = 0; tn < 4; ++tn)
        acc[ft][tn] = __builtin_amdgcn_mfma_f32_16x16x32_f16(af, bf[tn], acc[ft][tn], 0, 0, 0);
    }
  }
  float* Ob = OUT + (size_t)el * F_ * T_ + t0;
#pragma unroll
  for (int ft = 0; ft < 4; ++ft)
#pragma unroll
    for (int tn = 0; tn < 4; ++tn) {
      f32x4v c = acc[ft][tn];
      const int fb = wave * 64 + ft * 16 + quad * 4;
      const int tc = tn * 16 + nn;
      Ob[(size_t)(fb + 0) * T_ + tc] = c[0];
      Ob[(size_t)(fb + 1) * T_ + tc] = c[1];
      Ob[(size_t)(fb + 2) * T_ + tc] = c[2];
      Ob[(size_t)(fb + 3) * T_ + tc] = c[3];
    }
}

// K4: epilogue. Block = (l,f); thread = 4 t. red=(ksum-(S-dl)et)/dl, 6 pair
// |diff| sums over t, reduce, train/test max, write.
__global__ __launch_bounds__(256) void k4_epi(const float* __restrict__ OUT,
                                              const float* __restrict__ hdr,
                                              const float* __restrict__ dl,
                                              float* __restrict__ out) {
  __shared__ float rs[4][6];
  const int tid = threadIdx.x;
  const int l = blockIdx.x >> 8;
  const int f = blockIdx.x & 255;
  const float left = hdr[0], dg = hdr[1], scale = hdr[3];
  const int t = 4 * tid;
  float etv[4];
#pragma unroll
  for (int d = 0; d < 4; ++d) {
    float x = left + (float)(t + d) * dg;
    etv[d] = expf(-8.0f * x * x);
  }
  float red[E_][4];
#pragma unroll
  for (int e = 0; e < E_; ++e) {
    float4 ks = *(const float4*)(OUT + (((size_t)(e * L_ + l)) * F_ + f) * T_ + t);
    const float dlv = dl[e * L_ + l];
    const float zc = (float)S_ - dlv;
    const float idl = 1.0f / dlv;
    red[e][0] = (ks.x - zc * etv[0]) * idl;
    red[e][1] = (ks.y - zc * etv[1]) * idl;
    red[e][2] = (ks.z - zc * etv[2]) * idl;
    red[e][3] = (ks.w - zc * etv[3]) * idl;
  }
  float D[6];
  const int pa[6] = {0, 0, 0, 1, 1, 2};
  const int pb[6] = {1, 2, 3, 2, 3, 3};
#pragma unroll
  for (int p = 0; p < 6; ++p) {
    float s = 0.f;
#pragma unroll
    for (int d = 0; d < 4; ++d) s += fabsf(red[pa[p]][d] - red[pb[p]][d]);
    D[p] = s;
  }
#pragma unroll
  for (int off = 32; off; off >>= 1)
#pragma unroll
    for (int p = 0; p < 6; ++p) D[p] += __shfl_down(D[p], off);
  if ((tid & 63) == 0) {
#pragma unroll
    for (int p = 0; p < 6; ++p) rs[tid >> 6][p] = D[p];
  }
  __syncthreads();
  if (tid == 0) {
    float Tp[6];
#pragma unroll
    for (int p = 0; p < 6; ++p)
      Tp[p] = (rs[0][p] + rs[1][p] + rs[2][p] + rs[3][p]) * scale;
    float test = Tp[0];
#pragma unroll
    for (int p = 1; p < 6; ++p) test = fmaxf(test, Tp[p]);
    float train = fmaxf(fmaxf(Tp[1], Tp[2]), Tp[5]);
    out[l * F_ + f] = train;                 // train_results
    out[L_ * F_ + l * F_ + f] = test;        // test_results
  }
}

extern "C" void kernel_launch(void* const* d_in, const int* in_sizes, int n_in,
                              void* d_out, int out_size, void* d_ws, size_t ws_size,
                              hipStream_t stream) {
  const float* A  = (const float*)d_in[0];   // matrix (4,10,1024,256)
  const float* dl = (const float*)d_in[1];   // data_len (4,10)
  const float* P  = (const float*)d_in[2];   // params (256,256)
  float* out = (float*)d_out;
  float* ws = (float*)d_ws;
  float* hdr = ws;
  int* hdri = (int*)d_ws;
  unsigned int* slots = (unsigned int*)(ws + 16);
  __half* TTh = (__half*)(ws + OFF_TT);
  float* M   = ws + OFF_M;        // fp32 GEMM result (dead after k2)
  float* OUT = ws + OFF_M;        // OUT aliases M
  __half* Wh = (__half*)(ws + OFF_WH);

  (void)hipMemsetAsync(slots, 0xFF, 4, stream);      // min slot neutral
  (void)hipMemsetAsync(slots + 1, 0x00, 4, stream);  // max slot neutral

  k0_gemm<<<NROW / 64, 256, 0, stream>>>(A, P, M, slots);
  k1_setup<<<1, 64, 0, stream>>>(slots, hdr, hdri);
  k1b_tt<<<64, 256, 0, stream>>>(hdr, hdri, TTh);
  k2_bin<<<(E_ * L_) * (F_ / 16), 256, 0, stream>>>(M, hdr, Wh);
  k3_mfma<<<(E_ * L_) * 16, 256, 0, stream>>>((const _Float16*)Wh, (const _Float16*)TTh,
                                              hdri, OUT);
  k4_epi<<<L_ * F_, 256, 0, stream>>>(OUT, hdr, dl, out);
}

// Round 6
// 363.176 us; speedup vs baseline: 2.1002x; 1.2399x over previous
//
#include <hip/hip_runtime.h>
#include <hip/hip_fp16.h>
#include <math.h>

// Problem constants (fixed by reference setup_inputs)
#define E_ 4
#define L_ 10
#define S_ 1024
#define F_ 256
#define T_ 1024
#define NROW (E_*L_*S_)     // 40960 rows of the input GEMM
#define KPAD2 384           // left pad of each padded W row (halfs), mult of 8
#define WROW 1920           // padded W row stride in halfs (384+1024+512)
#define TTW  864            // Toeplitz block width (a-dim), covers 2*K4max+96

// workspace layout (float indices). OUT aliases M (M dead after k2).
#define OFF_TT  64                       // f16 TT[64][864] = 55296 halfs = 27648 floats
#define OFF_M   32768                    // fp32 M, 40960*256 floats (= OUT alias)
#define OFF_WH  (32768 + (size_t)NROW * F_)        // f16 padded W planes
#define OFF_PT  (OFF_WH + (size_t)40 * F_ * WROW / 2)  // f16 PT[256][256] = 32768 floats

typedef _Float16 half8 __attribute__((ext_vector_type(8)));
typedef float f32x4v __attribute__((ext_vector_type(4)));

__device__ __forceinline__ unsigned int encf(float x) {
  unsigned int b = __float_as_uint(x);
  return (b & 0x80000000u) ? ~b : (b | 0x80000000u);
}
__device__ __forceinline__ float decf(unsigned int u) {
  unsigned int b = (u & 0x80000000u) ? (u ^ 0x80000000u) : ~u;
  return __uint_as_float(b);
}

// K_pt: PT[c][k] = (f16)P[k][c]. Coalesced reads, scattered 2B writes (tiny).
__global__ __launch_bounds__(256) void k_pt(const float* __restrict__ P,
                                            _Float16* __restrict__ PT) {
  const int k = blockIdx.x;
  const int c = threadIdx.x;
  PT[(size_t)c * F_ + k] = (_Float16)P[(size_t)k * F_ + c];
}

// K0: m = matrix @ params via MFMA f16 with hi/lo split (near-fp32 accuracy):
// m = A_hi@P + A_lo@P, A_hi=f16(A), A_lo=f16(A-A_hi). Fused global min/max.
// Block: 64 rows x 256 cols; wave w owns cols [64w,64w+64): 4x4 16x16 tiles.
__global__ __launch_bounds__(256) void k0_mfma(const float* __restrict__ A,
                                               const _Float16* __restrict__ PT,
                                               float* __restrict__ M,
                                               unsigned int* __restrict__ slots) {
  __shared__ __align__(16) _Float16 Ahi[64][40];   // 5 KB, 80 B row stride
  __shared__ __align__(16) _Float16 Alo[64][40];   // 5 KB
  __shared__ __align__(16) _Float16 Bl[256][40];   // 20 KB
  const int tid = threadIdx.x;
  const int wave = tid >> 6, lane = tid & 63;
  const int nn = lane & 15, quad = lane >> 4;
  const int row0 = blockIdx.x * 64;
  f32x4v acc[4][4];
#pragma unroll
  for (int rt = 0; rt < 4; ++rt)
#pragma unroll
    for (int ct = 0; ct < 4; ++ct) acc[rt][ct] = (f32x4v){0.f, 0.f, 0.f, 0.f};
  for (int kc = 0; kc < 8; ++kc) {
    __syncthreads();
    {  // stage A chunk 64 rows x 32 k: fp32 -> f16 hi/lo
      const int r = tid >> 2, part = tid & 3;
      const float* src = A + (size_t)(row0 + r) * F_ + kc * 32 + part * 8;
      float4 v0 = ((const float4*)src)[0];
      float4 v1 = ((const float4*)src)[1];
      float vv[8] = {v0.x, v0.y, v0.z, v0.w, v1.x, v1.y, v1.z, v1.w};
      half8 hh, hl;
#pragma unroll
      for (int j = 0; j < 8; ++j) {
        _Float16 h = (_Float16)vv[j];
        hh[j] = h;
        hl[j] = (_Float16)(vv[j] - (float)h);
      }
      *(half8*)&Ahi[r][part * 8] = hh;
      *(half8*)&Alo[r][part * 8] = hl;
    }
    {  // stage B chunk: Bl[c][0..32) = PT[c][kc*32..+32)
      const int4* bs = (const int4*)(PT + (size_t)tid * F_ + kc * 32);
      int4 b0 = bs[0], b1 = bs[1], b2 = bs[2], b3 = bs[3];
      int4* bd = (int4*)&Bl[tid][0];
      bd[0] = b0; bd[1] = b1; bd[2] = b2; bd[3] = b3;
    }
    __syncthreads();
    half8 afh[4], afl[4], bf[4];
#pragma unroll
    for (int rt = 0; rt < 4; ++rt) {
      afh[rt] = *(const half8*)&Ahi[rt * 16 + nn][quad * 8];
      afl[rt] = *(const half8*)&Alo[rt * 16 + nn][quad * 8];
    }
#pragma unroll
    for (int ct = 0; ct < 4; ++ct)
      bf[ct] = *(const half8*)&Bl[wave * 64 + ct * 16 + nn][quad * 8];
#pragma unroll
    for (int rt = 0; rt < 4; ++rt)
#pragma unroll
      for (int ct = 0; ct < 4; ++ct) {
        acc[rt][ct] = __builtin_amdgcn_mfma_f32_16x16x32_f16(afh[rt], bf[ct], acc[rt][ct], 0, 0, 0);
        acc[rt][ct] = __builtin_amdgcn_mfma_f32_16x16x32_f16(afl[rt], bf[ct], acc[rt][ct], 0, 0, 0);
      }
  }
  // store M + fused min/max. C layout: row = quad*4+j, col = nn.
  float vmin = 3.4e38f, vmax = -3.4e38f;
#pragma unroll
  for (int rt = 0; rt < 4; ++rt)
#pragma unroll
    for (int ct = 0; ct < 4; ++ct) {
      f32x4v c = acc[rt][ct];
      const int col = wave * 64 + ct * 16 + nn;
      const int rb = row0 + rt * 16 + quad * 4;
#pragma unroll
      for (int j = 0; j < 4; ++j) {
        M[(size_t)(rb + j) * F_ + col] = c[j];
        vmin = fminf(vmin, c[j]);
        vmax = fmaxf(vmax, c[j]);
      }
    }
#pragma unroll
  for (int off = 32; off; off >>= 1) {
    vmin = fminf(vmin, __shfl_down(vmin, off));
    vmax = fmaxf(vmax, __shfl_down(vmax, off));
  }
  if (lane == 0) {
    atomicMin(&slots[0], encf(vmin));
    atomicMax(&slots[1], encf(vmax));
  }
}

// K1: grid constants only (1 block).
__global__ __launch_bounds__(64) void k1_setup(const unsigned int* __restrict__ slots,
                                               float* __restrict__ hdr,
                                               int* __restrict__ hdri) {
  if (threadIdx.x == 0) {
    const float left = decf(slots[0]);
    const float right = decf(slots[1]);
    const float dg = (right - left) / 1023.0f;    // linspace step (1024 pts)
    const float inv_dg = 1.0f / dg;
    const float delta = (right - left) / 1024.0f; // reference's delta
    const float divisor = 0.62665706865775006f;   // sqrt(2*pi)*0.25
    const float scale = delta * 0.5f / divisor;
    int kmax = (int)(2.39792f * inv_dg) + 1;      // exp(-8u^2)<1e-20 beyond
    if (kmax > 368) kmax = 368;
    const int K4 = (kmax + 8) & ~7;               // mult of 8, > kmax, <= 376
    hdr[0] = left; hdr[1] = dg; hdr[2] = inv_dg; hdr[3] = scale;
    hdri[4] = K4; hdri[5] = kmax;
  }
}

// K1b: Toeplitz block TT[b][ak] = G(b + K4 - ak), f16. One block per b row.
__global__ __launch_bounds__(256) void k1b_tt(const float* __restrict__ hdr,
                                              const int* __restrict__ hdri,
                                              __half* __restrict__ TT) {
  const int b = blockIdx.x;
  const float dg = hdr[1];
  const int K4 = hdri[4], kmax = hdri[5];
  for (int ak = threadIdx.x; ak < TTW; ak += 256) {
    int d = b + K4 - ak;
    int ad = d < 0 ? -d : d;
    float u = (float)d * dg;
    float v = (ad <= kmax) ? expf(-8.0f * u * u) : 0.0f;
    TT[(size_t)b * TTW + ak] = __float2half(v);
  }
}

// K2: linear binning into fp32 LDS bins, then write padded f16 W rows.
__global__ __launch_bounds__(256) void k2_bin(const float* __restrict__ M,
                                              const float* __restrict__ hdr,
                                              __half* __restrict__ Wh) {
  __shared__ float wl[16][T_];   // 64 KB
  const int tid = threadIdx.x;
  const int el = blockIdx.x >> 4;
  const int fg = blockIdx.x & 15;
  {
    float4* z = (float4*)&wl[0][0];
    for (int i = tid; i < 16 * T_ / 4; i += 256) z[i] = make_float4(0.f, 0.f, 0.f, 0.f);
  }
  __syncthreads();
  const float left = hdr[0];
  const float inv_dg = hdr[2];
  const int fs = tid & 15;
  const int ss = tid >> 4;
  const float* base = M + (size_t)el * S_ * F_ + fg * 16 + fs;
  for (int s = ss; s < S_; s += 16) {
    float v = base[(size_t)s * F_];
    float p = (v - left) * inv_dg;
    int j = (int)p;
    if (j > 1022) j = 1022;
    float a = p - (float)j;
    atomicAdd(&wl[fs][j], 1.0f - a);
    atomicAdd(&wl[fs][j + 1], a);
  }
  __syncthreads();
  __half* wrow = Wh + ((size_t)el * F_ + fg * 16) * WROW;
  // main region: 16 rows x 1024 halfs
  for (int i = tid; i < 16 * 512; i += 256) {
    int r = i >> 9, c2 = i & 511;
    *(__half2*)(wrow + (size_t)r * WROW + KPAD2 + 2 * c2) =
        __floats2half2_rn(wl[r][2 * c2], wl[r][2 * c2 + 1]);
  }
  // pads: left [0,384) = 192 half2, right [1408,1920) = 256 half2 -> 448/row
  for (int i = tid; i < 16 * 448; i += 256) {
    int r = i / 448, p = i % 448;
    int col = (p < 192) ? 2 * p : (1408 + 2 * (p - 192));
    *(__half2*)(wrow + (size_t)r * WROW + col) = __floats2half2_rn(0.f, 0.f);
  }
}

// K3: banded-Toeplitz GEMM via MFMA f32_16x16x32_f16.
// Block = (el, t-tile of 64): OUT[el][f=0..255][t0..t0+63] = W x TT.
// 4 waves; wave w owns f in [64w, 64w+64): 4x4 grid of 16x16 MFMA tiles.
__global__ __launch_bounds__(256) void k3_mfma(const _Float16* __restrict__ Wh,
                                               const _Float16* __restrict__ TT,
                                               const int* __restrict__ hdri,
                                               float* __restrict__ OUT) {
  __shared__ __align__(16) _Float16 Wl[256][40];  // 20 KB, row 80 B
  const int tid = threadIdx.x;
  const int wave = tid >> 6, lane = tid & 63;
  const int nn = lane & 15, quad = lane >> 4;
  const int el = blockIdx.x >> 4;
  const int t0 = (blockIdx.x & 15) << 6;
  const int K4 = hdri[4];
  const int nkc = (2 * K4 + 64 + 31) >> 5;
  const _Float16* Wp = Wh + (size_t)el * F_ * WROW + (KPAD2 - K4 + t0);
  f32x4v acc[4][4];
#pragma unroll
  for (int ft = 0; ft < 4; ++ft)
#pragma unroll
    for (int tn = 0; tn < 4; ++tn) acc[ft][tn] = (f32x4v){0.f, 0.f, 0.f, 0.f};
  for (int kc = 0; kc < nkc; ++kc) {
    __syncthreads();
    {
      const int4* s = (const int4*)(Wp + (size_t)tid * WROW + kc * 32);
      int4 v0 = s[0], v1 = s[1], v2 = s[2], v3 = s[3];
      int4* d = (int4*)&Wl[tid][0];
      d[0] = v0; d[1] = v1; d[2] = v2; d[3] = v3;
    }
    __syncthreads();
    half8 bf[4];
#pragma unroll
    for (int tn = 0; tn < 4; ++tn)
      bf[tn] = *(const half8*)(TT + (size_t)(tn * 16 + nn) * TTW + kc * 32 + quad * 8);
#pragma unroll
    for (int ft = 0; ft < 4; ++ft) {
      half8 af = *(const half8*)&Wl[wave * 64 + ft * 16 + nn][quad * 8];
#pragma unroll
      for (int tn = 0; tn < 4; ++tn)
        acc[ft][tn] = __builtin_amdgcn_mfma_f32_16x16x32_f16(af, bf[tn], acc[ft][tn], 0, 0, 0);
    }
  }
  float* Ob = OUT + (size_t)el * F_ * T_ + t0;
#pragma unroll
  for (int ft = 0; ft < 4; ++ft)
#pragma unroll
    for (int tn = 0; tn < 4; ++tn) {
      f32x4v c = acc[ft][tn];
      const int fb = wave * 64 + ft * 16 + quad * 4;
      const int tc = tn * 16 + nn;
      Ob[(size_t)(fb + 0) * T_ + tc] = c[0];
      Ob[(size_t)(fb + 1) * T_ + tc] = c[1];
      Ob[(size_t)(fb + 2) * T_ + tc] = c[2];
      Ob[(size_t)(fb + 3) * T_ + tc] = c[3];
    }
}

// K4: epilogue. Block = (l,f); thread = 4 t. red=(ksum-(S-dl)et)/dl, 6 pair
// |diff| sums over t, reduce, train/test max, write.
__global__ __launch_bounds__(256) void k4_epi(const float* __restrict__ OUT,
                                              const float* __restrict__ hdr,
                                              const float* __restrict__ dl,
                                              float* __restrict__ out) {
  __shared__ float rs[4][6];
  const int tid = threadIdx.x;
  const int l = blockIdx.x >> 8;
  const int f = blockIdx.x & 255;
  const float left = hdr[0], dg = hdr[1], scale = hdr[3];
  const int t = 4 * tid;
  float etv[4];
#pragma unroll
  for (int d = 0; d < 4; ++d) {
    float x = left + (float)(t + d) * dg;
    etv[d] = expf(-8.0f * x * x);
  }
  float red[E_][4];
#pragma unroll
  for (int e = 0; e < E_; ++e) {
    float4 ks = *(const float4*)(OUT + (((size_t)(e * L_ + l)) * F_ + f) * T_ + t);
    const float dlv = dl[e * L_ + l];
    const float zc = (float)S_ - dlv;
    const float idl = 1.0f / dlv;
    red[e][0] = (ks.x - zc * etv[0]) * idl;
    red[e][1] = (ks.y - zc * etv[1]) * idl;
    red[e][2] = (ks.z - zc * etv[2]) * idl;
    red[e][3] = (ks.w - zc * etv[3]) * idl;
  }
  float D[6];
  const int pa[6] = {0, 0, 0, 1, 1, 2};
  const int pb[6] = {1, 2, 3, 2, 3, 3};
#pragma unroll
  for (int p = 0; p < 6; ++p) {
    float s = 0.f;
#pragma unroll
    for (int d = 0; d < 4; ++d) s += fabsf(red[pa[p]][d] - red[pb[p]][d]);
    D[p] = s;
  }
#pragma unroll
  for (int off = 32; off; off >>= 1)
#pragma unroll
    for (int p = 0; p < 6; ++p) D[p] += __shfl_down(D[p], off);
  if ((tid & 63) == 0) {
#pragma unroll
    for (int p = 0; p < 6; ++p) rs[tid >> 6][p] = D[p];
  }
  __syncthreads();
  if (tid == 0) {
    float Tp[6];
#pragma unroll
    for (int p = 0; p < 6; ++p)
      Tp[p] = (rs[0][p] + rs[1][p] + rs[2][p] + rs[3][p]) * scale;
    float test = Tp[0];
#pragma unroll
    for (int p = 1; p < 6; ++p) test = fmaxf(test, Tp[p]);
    float train = fmaxf(fmaxf(Tp[1], Tp[2]), Tp[5]);
    out[l * F_ + f] = train;                 // train_results
    out[L_ * F_ + l * F_ + f] = test;        // test_results
  }
}

extern "C" void kernel_launch(void* const* d_in, const int* in_sizes, int n_in,
                              void* d_out, int out_size, void* d_ws, size_t ws_size,
                              hipStream_t stream) {
  const float* A  = (const float*)d_in[0];   // matrix (4,10,1024,256)
  const float* dl = (const float*)d_in[1];   // data_len (4,10)
  const float* P  = (const float*)d_in[2];   // params (256,256)
  float* out = (float*)d_out;
  float* ws = (float*)d_ws;
  float* hdr = ws;
  int* hdri = (int*)d_ws;
  unsigned int* slots = (unsigned int*)(ws + 16);
  __half* TTh = (__half*)(ws + OFF_TT);
  float* M   = ws + OFF_M;        // fp32 GEMM result (dead after k2)
  float* OUT = ws + OFF_M;        // OUT aliases M
  __half* Wh = (__half*)(ws + OFF_WH);
  _Float16* PT = (_Float16*)(ws + OFF_PT);

  (void)hipMemsetAsync(slots, 0xFF, 4, stream);      // min slot neutral
  (void)hipMemsetAsync(slots + 1, 0x00, 4, stream);  // max slot neutral

  k_pt<<<F_, 256, 0, stream>>>(P, PT);
  k0_mfma<<<NROW / 64, 256, 0, stream>>>(A, PT, M, slots);
  k1_setup<<<1, 64, 0, stream>>>(slots, hdr, hdri);
  k1b_tt<<<64, 256, 0, stream>>>(hdr, hdri, TTh);
  k2_bin<<<(E_ * L_) * (F_ / 16), 256, 0, stream>>>(M, hdr, Wh);
  k3_mfma<<<(E_ * L_) * 16, 256, 0, stream>>>((const _Float16*)Wh, (const _Float16*)TTh,
                                              hdri, OUT);
  k4_epi<<<L_ * F_, 256, 0, stream>>>(OUT, hdr, dl, out);
}

// Round 7
// 341.471 us; speedup vs baseline: 2.2337x; 1.0636x over previous
//
#include <hip/hip_runtime.h>
#include <hip/hip_fp16.h>
#include <math.h>

// Problem constants (fixed by reference setup_inputs)
#define E_ 4
#define L_ 10
#define S_ 1024
#define F_ 256
#define T_ 1024
#define NROW (E_*L_*S_)     // 40960 rows of the input GEMM
#define KPAD2 384           // left pad of each padded W row (halfs), mult of 8
#define WROW 1920           // padded W row stride in halfs (384+1024+512)
#define TTW  864            // Toeplitz block width (a-dim), covers 2*K4max+96

// workspace layout (float indices). OUT aliases M (M dead after k2).
#define OFF_TT  64                       // f16 TT[64][864] = 55296 halfs = 27648 floats
#define OFF_M   32768                    // fp32 M, 40960*256 floats (= OUT alias)
#define OFF_WH  (32768 + (size_t)NROW * F_)        // f16 padded W planes
#define OFF_PT  (OFF_WH + (size_t)40 * F_ * WROW / 2)  // f16 PT[256][256] = 32768 floats

typedef _Float16 half8 __attribute__((ext_vector_type(8)));
typedef float f32x4v __attribute__((ext_vector_type(4)));

__device__ __forceinline__ unsigned int encf(float x) {
  unsigned int b = __float_as_uint(x);
  return (b & 0x80000000u) ? ~b : (b | 0x80000000u);
}
__device__ __forceinline__ float decf(unsigned int u) {
  unsigned int b = (u & 0x80000000u) ? (u ^ 0x80000000u) : ~u;
  return __uint_as_float(b);
}

// K_pt: PT[c][k] = (f16)P[k][c]. Coalesced reads, scattered 2B writes (tiny).
__global__ __launch_bounds__(256) void k_pt(const float* __restrict__ P,
                                            _Float16* __restrict__ PT) {
  const int k = blockIdx.x;
  const int c = threadIdx.x;
  PT[(size_t)c * F_ + k] = (_Float16)P[(size_t)k * F_ + c];
}

// K_pad: zero the static pad regions of Wh (left 384 + right 512 halfs per row).
// Per row of 240 int4s: zero [0,48) and [176,240) -> 112 int4s/row.
__global__ __launch_bounds__(256) void k_pad(int4* __restrict__ Whv) {
  const size_t total = (size_t)40 * F_ * 112;
  const int4 z = make_int4(0, 0, 0, 0);
  for (size_t i = (size_t)blockIdx.x * 256 + threadIdx.x; i < total;
       i += (size_t)gridDim.x * 256) {
    size_t row = i / 112;
    int k = (int)(i % 112);
    int off = (k < 48) ? k : (128 + k);
    Whv[row * 240 + off] = z;
  }
}

// K0: m = matrix @ params via MFMA f16 with hi/lo split (near-fp32 accuracy):
// m = A_hi@P + A_lo@P, A_hi=f16(A), A_lo=f16(A-A_hi). Fused global min/max.
// Block: 64 rows x 256 cols; wave w owns cols [64w,64w+64): 4x4 16x16 tiles.
__global__ __launch_bounds__(256) void k0_mfma(const float* __restrict__ A,
                                               const _Float16* __restrict__ PT,
                                               float* __restrict__ M,
                                               unsigned int* __restrict__ slots) {
  __shared__ __align__(16) _Float16 Ahi[64][40];   // 5 KB, 80 B row stride
  __shared__ __align__(16) _Float16 Alo[64][40];   // 5 KB
  __shared__ __align__(16) _Float16 Bl[256][40];   // 20 KB
  const int tid = threadIdx.x;
  const int wave = tid >> 6, lane = tid & 63;
  const int nn = lane & 15, quad = lane >> 4;
  const int row0 = blockIdx.x * 64;
  f32x4v acc[4][4];
#pragma unroll
  for (int rt = 0; rt < 4; ++rt)
#pragma unroll
    for (int ct = 0; ct < 4; ++ct) acc[rt][ct] = (f32x4v){0.f, 0.f, 0.f, 0.f};
  for (int kc = 0; kc < 8; ++kc) {
    __syncthreads();
    {  // stage A chunk 64 rows x 32 k: fp32 -> f16 hi/lo
      const int r = tid >> 2, part = tid & 3;
      const float* src = A + (size_t)(row0 + r) * F_ + kc * 32 + part * 8;
      float4 v0 = ((const float4*)src)[0];
      float4 v1 = ((const float4*)src)[1];
      float vv[8] = {v0.x, v0.y, v0.z, v0.w, v1.x, v1.y, v1.z, v1.w};
      half8 hh, hl;
#pragma unroll
      for (int j = 0; j < 8; ++j) {
        _Float16 h = (_Float16)vv[j];
        hh[j] = h;
        hl[j] = (_Float16)(vv[j] - (float)h);
      }
      *(half8*)&Ahi[r][part * 8] = hh;
      *(half8*)&Alo[r][part * 8] = hl;
    }
    {  // stage B chunk: Bl[c][0..32) = PT[c][kc*32..+32)
      const int4* bs = (const int4*)(PT + (size_t)tid * F_ + kc * 32);
      int4 b0 = bs[0], b1 = bs[1], b2 = bs[2], b3 = bs[3];
      int4* bd = (int4*)&Bl[tid][0];
      bd[0] = b0; bd[1] = b1; bd[2] = b2; bd[3] = b3;
    }
    __syncthreads();
    half8 afh[4], afl[4], bf[4];
#pragma unroll
    for (int rt = 0; rt < 4; ++rt) {
      afh[rt] = *(const half8*)&Ahi[rt * 16 + nn][quad * 8];
      afl[rt] = *(const half8*)&Alo[rt * 16 + nn][quad * 8];
    }
#pragma unroll
    for (int ct = 0; ct < 4; ++ct)
      bf[ct] = *(const half8*)&Bl[wave * 64 + ct * 16 + nn][quad * 8];
#pragma unroll
    for (int rt = 0; rt < 4; ++rt)
#pragma unroll
      for (int ct = 0; ct < 4; ++ct) {
        acc[rt][ct] = __builtin_amdgcn_mfma_f32_16x16x32_f16(afh[rt], bf[ct], acc[rt][ct], 0, 0, 0);
        acc[rt][ct] = __builtin_amdgcn_mfma_f32_16x16x32_f16(afl[rt], bf[ct], acc[rt][ct], 0, 0, 0);
      }
  }
  // store M + fused min/max. C layout: row = quad*4+j, col = nn.
  float vmin = 3.4e38f, vmax = -3.4e38f;
#pragma unroll
  for (int rt = 0; rt < 4; ++rt)
#pragma unroll
    for (int ct = 0; ct < 4; ++ct) {
      f32x4v c = acc[rt][ct];
      const int col = wave * 64 + ct * 16 + nn;
      const int rb = row0 + rt * 16 + quad * 4;
#pragma unroll
      for (int j = 0; j < 4; ++j) {
        M[(size_t)(rb + j) * F_ + col] = c[j];
        vmin = fminf(vmin, c[j]);
        vmax = fmaxf(vmax, c[j]);
      }
    }
#pragma unroll
  for (int off = 32; off; off >>= 1) {
    vmin = fminf(vmin, __shfl_down(vmin, off));
    vmax = fmaxf(vmax, __shfl_down(vmax, off));
  }
  if (lane == 0) {
    atomicMin(&slots[0], encf(vmin));
    atomicMax(&slots[1], encf(vmax));
  }
}

// K1: grid constants only (1 block).
__global__ __launch_bounds__(64) void k1_setup(const unsigned int* __restrict__ slots,
                                               float* __restrict__ hdr,
                                               int* __restrict__ hdri) {
  if (threadIdx.x == 0) {
    const float left = decf(slots[0]);
    const float right = decf(slots[1]);
    const float dg = (right - left) / 1023.0f;    // linspace step (1024 pts)
    const float inv_dg = 1.0f / dg;
    const float delta = (right - left) / 1024.0f; // reference's delta
    const float divisor = 0.62665706865775006f;   // sqrt(2*pi)*0.25
    const float scale = delta * 0.5f / divisor;
    int kmax = (int)(2.39792f * inv_dg) + 1;      // exp(-8u^2)<1e-20 beyond
    if (kmax > 368) kmax = 368;
    const int K4 = (kmax + 8) & ~7;               // mult of 8, > kmax, <= 376
    hdr[0] = left; hdr[1] = dg; hdr[2] = inv_dg; hdr[3] = scale;
    hdri[4] = K4; hdri[5] = kmax;
  }
}

// K1b: Toeplitz block TT[b][ak] = G(b + K4 - ak), f16. One block per b row.
__global__ __launch_bounds__(256) void k1b_tt(const float* __restrict__ hdr,
                                              const int* __restrict__ hdri,
                                              __half* __restrict__ TT) {
  const int b = blockIdx.x;
  const float dg = hdr[1];
  const int K4 = hdri[4], kmax = hdri[5];
  for (int ak = threadIdx.x; ak < TTW; ak += 256) {
    int d = b + K4 - ak;
    int ad = d < 0 ? -d : d;
    float u = (float)d * dg;
    float v = (ad <= kmax) ? expf(-8.0f * u * u) : 0.0f;
    TT[(size_t)b * TTW + ak] = __float2half(v);
  }
}

// K2: linear binning. Block = (el, 8-f group): 8x1024 fp32 bins in LDS (32 KB,
// 5 blocks/CU). float2 loads, b128 f16 stores (pads pre-zeroed by k_pad).
__global__ __launch_bounds__(256) void k2_bin(const float* __restrict__ M,
                                              const float* __restrict__ hdr,
                                              __half* __restrict__ Wh) {
  __shared__ float wl[8][T_];   // 32 KB
  const int tid = threadIdx.x;
  const int el = blockIdx.x >> 5;
  const int fg = blockIdx.x & 31;
  {
    float4* z = (float4*)&wl[0][0];
    for (int i = tid; i < 8 * T_ / 4; i += 256) z[i] = make_float4(0.f, 0.f, 0.f, 0.f);
  }
  __syncthreads();
  const float left = hdr[0];
  const float inv_dg = hdr[2];
  const int fp = tid & 3;               // f-pair index
  const int ss = tid >> 2;              // 0..63
  const float* base = M + (size_t)el * S_ * F_ + fg * 8 + fp * 2;
  for (int s = ss; s < S_; s += 64) {
    float2 v = *(const float2*)(base + (size_t)s * F_);
    float vv[2] = {v.x, v.y};
#pragma unroll
    for (int c = 0; c < 2; ++c) {
      float p = (vv[c] - left) * inv_dg;
      int j = (int)p;
      if (j > 1022) j = 1022;
      float a = p - (float)j;
      atomicAdd(&wl[fp * 2 + c][j], 1.0f - a);
      atomicAdd(&wl[fp * 2 + c][j + 1], a);
    }
  }
  __syncthreads();
  _Float16* wrow = (_Float16*)Wh + ((size_t)el * F_ + fg * 8) * WROW + KPAD2;
#pragma unroll
  for (int q = 0; q < 4; ++q) {
    int idx = tid + 256 * q;
    int r = idx >> 7, c8 = (idx & 127) * 8;
    float4 a = *(const float4*)&wl[r][c8];
    float4 b = *(const float4*)&wl[r][c8 + 4];
    half8 h;
    h[0] = (_Float16)a.x; h[1] = (_Float16)a.y; h[2] = (_Float16)a.z; h[3] = (_Float16)a.w;
    h[4] = (_Float16)b.x; h[5] = (_Float16)b.y; h[6] = (_Float16)b.z; h[7] = (_Float16)b.w;
    *(half8*)(wrow + (size_t)r * WROW + c8) = h;
  }
}

// K3: banded-Toeplitz GEMM via MFMA f32_16x16x32_f16.
// Block = (el, t-tile of 64): OUT[el][f=0..255][t0..t0+63] = W x TT.
// 4 waves; wave w owns f in [64w, 64w+64): 4x4 grid of 16x16 MFMA tiles.
__global__ __launch_bounds__(256) void k3_mfma(const _Float16* __restrict__ Wh,
                                               const _Float16* __restrict__ TT,
                                               const int* __restrict__ hdri,
                                               float* __restrict__ OUT) {
  __shared__ __align__(16) _Float16 Wl[256][40];  // 20 KB, row 80 B
  const int tid = threadIdx.x;
  const int wave = tid >> 6, lane = tid & 63;
  const int nn = lane & 15, quad = lane >> 4;
  const int el = blockIdx.x >> 4;
  const int t0 = (blockIdx.x & 15) << 6;
  const int K4 = hdri[4];
  const int nkc = (2 * K4 + 64 + 31) >> 5;
  const _Float16* Wp = Wh + (size_t)el * F_ * WROW + (KPAD2 - K4 + t0);
  f32x4v acc[4][4];
#pragma unroll
  for (int ft = 0; ft < 4; ++ft)
#pragma unroll
    for (int tn = 0; tn < 4; ++tn) acc[ft][tn] = (f32x4v){0.f, 0.f, 0.f, 0.f};
  for (int kc = 0; kc < nkc; ++kc) {
    __syncthreads();
    {
      const int4* s = (const int4*)(Wp + (size_t)tid * WROW + kc * 32);
      int4 v0 = s[0], v1 = s[1], v2 = s[2], v3 = s[3];
      int4* d = (int4*)&Wl[tid][0];
      d[0] = v0; d[1] = v1; d[2] = v2; d[3] = v3;
    }
    __syncthreads();
    half8 bf[4];
#pragma unroll
    for (int tn = 0; tn < 4; ++tn)
      bf[tn] = *(const half8*)(TT + (size_t)(tn * 16 + nn) * TTW + kc * 32 + quad * 8);
#pragma unroll
    for (int ft = 0; ft < 4; ++ft) {
      half8 af = *(const half8*)&Wl[wave * 64 + ft * 16 + nn][quad * 8];
#pragma unroll
      for (int tn = 0; tn < 4; ++tn)
        acc[ft][tn] = __builtin_amdgcn_mfma_f32_16x16x32_f16(af, bf[tn], acc[ft][tn], 0, 0, 0);
    }
  }
  float* Ob = OUT + (size_t)el * F_ * T_ + t0;
#pragma unroll
  for (int ft = 0; ft < 4; ++ft)
#pragma unroll
    for (int tn = 0; tn < 4; ++tn) {
      f32x4v c = acc[ft][tn];
      const int fb = wave * 64 + ft * 16 + quad * 4;
      const int tc = tn * 16 + nn;
      Ob[(size_t)(fb + 0) * T_ + tc] = c[0];
      Ob[(size_t)(fb + 1) * T_ + tc] = c[1];
      Ob[(size_t)(fb + 2) * T_ + tc] = c[2];
      Ob[(size_t)(fb + 3) * T_ + tc] = c[3];
    }
}

// K4: epilogue. Block = (l,f); thread = 4 t. red=(ksum-(S-dl)et)/dl, 6 pair
// |diff| sums over t, reduce, train/test max, write.
__global__ __launch_bounds__(256) void k4_epi(const float* __restrict__ OUT,
                                              const float* __restrict__ hdr,
                                              const float* __restrict__ dl,
                                              float* __restrict__ out) {
  __shared__ float rs[4][6];
  const int tid = threadIdx.x;
  const int l = blockIdx.x >> 8;
  const int f = blockIdx.x & 255;
  const float left = hdr[0], dg = hdr[1], scale = hdr[3];
  const int t = 4 * tid;
  float etv[4];
#pragma unroll
  for (int d = 0; d < 4; ++d) {
    float x = left + (float)(t + d) * dg;
    etv[d] = expf(-8.0f * x * x);
  }
  float red[E_][4];
#pragma unroll
  for (int e = 0; e < E_; ++e) {
    float4 ks = *(const float4*)(OUT + (((size_t)(e * L_ + l)) * F_ + f) * T_ + t);
    const float dlv = dl[e * L_ + l];
    const float zc = (float)S_ - dlv;
    const float idl = 1.0f / dlv;
    red[e][0] = (ks.x - zc * etv[0]) * idl;
    red[e][1] = (ks.y - zc * etv[1]) * idl;
    red[e][2] = (ks.z - zc * etv[2]) * idl;
    red[e][3] = (ks.w - zc * etv[3]) * idl;
  }
  float D[6];
  const int pa[6] = {0, 0, 0, 1, 1, 2};
  const int pb[6] = {1, 2, 3, 2, 3, 3};
#pragma unroll
  for (int p = 0; p < 6; ++p) {
    float s = 0.f;
#pragma unroll
    for (int d = 0; d < 4; ++d) s += fabsf(red[pa[p]][d] - red[pb[p]][d]);
    D[p] = s;
  }
#pragma unroll
  for (int off = 32; off; off >>= 1)
#pragma unroll
    for (int p = 0; p < 6; ++p) D[p] += __shfl_down(D[p], off);
  if ((tid & 63) == 0) {
#pragma unroll
    for (int p = 0; p < 6; ++p) rs[tid >> 6][p] = D[p];
  }
  __syncthreads();
  if (tid == 0) {
    float Tp[6];
#pragma unroll
    for (int p = 0; p < 6; ++p)
      Tp[p] = (rs[0][p] + rs[1][p] + rs[2][p] + rs[3][p]) * scale;
    float test = Tp[0];
#pragma unroll
    for (int p = 1; p < 6; ++p) test = fmaxf(test, Tp[p]);
    float train = fmaxf(fmaxf(Tp[1], Tp[2]), Tp[5]);
    out[l * F_ + f] = train;                 // train_results
    out[L_ * F_ + l * F_ + f] = test;        // test_results
  }
}

extern "C" void kernel_launch(void* const* d_in, const int* in_sizes, int n_in,
                              void* d_out, int out_size, void* d_ws, size_t ws_size,
                              hipStream_t stream) {
  const float* A  = (const float*)d_in[0];   // matrix (4,10,1024,256)
  const float* dl = (const float*)d_in[1];   // data_len (4,10)
  const float* P  = (const float*)d_in[2];   // params (256,256)
  float* out = (float*)d_out;
  float* ws = (float*)d_ws;
  float* hdr = ws;
  int* hdri = (int*)d_ws;
  unsigned int* slots = (unsigned int*)(ws + 16);
  __half* TTh = (__half*)(ws + OFF_TT);
  float* M   = ws + OFF_M;        // fp32 GEMM result (dead after k2)
  float* OUT = ws + OFF_M;        // OUT aliases M
  __half* Wh = (__half*)(ws + OFF_WH);
  _Float16* PT = (_Float16*)(ws + OFF_PT);

  (void)hipMemsetAsync(slots, 0xFF, 4, stream);      // min slot neutral
  (void)hipMemsetAsync(slots + 1, 0x00, 4, stream);  // max slot neutral

  k_pt<<<F_, 256, 0, stream>>>(P, PT);
  k_pad<<<1120, 256, 0, stream>>>((int4*)Wh);
  k0_mfma<<<NROW / 64, 256, 0, stream>>>(A, PT, M, slots);
  k1_setup<<<1, 64, 0, stream>>>(slots, hdr, hdri);
  k1b_tt<<<64, 256, 0, stream>>>(hdr, hdri, TTh);
  k2_bin<<<(E_ * L_) * (F_ / 8), 256, 0, stream>>>(M, hdr, Wh);
  k3_mfma<<<(E_ * L_) * 16, 256, 0, stream>>>((const _Float16*)Wh, (const _Float16*)TTh,
                                              hdri, OUT);
  k4_epi<<<L_ * F_, 256, 0, stream>>>(OUT, hdr, dl, out);
}